// Round 4
// baseline (106.070 us; speedup 1.0000x reference)
//
#include <hip/hip_runtime.h>
#include <hip/hip_fp16.h>

// LogicLayer: out[b,n] = C0[n] + C1[n]*a + C2[n]*b + C3[n]*a*b,
//   a = x[b, idx_a[n]], b = x[b, idx_b[n]], C = linear combos of softmax(w[n]).
//
// R8: R7 post-mortem — allocator ignored __launch_bounds__(1024,4) and kept
// a 64-VGPR / 8-waves-per-EU target, spilling the prefetch state (WRITE_SIZE
// 219 MB vs 131 ideal). Fix: pin amdgpu_waves_per_eu(4,4) -> 128-VGPR budget
// (state audit ~116 regs). Also drop nontemporal hints (R4's plain-load path
// sustained 4.3 TB/s vs 3.8 with nt). Structure unchanged from R7:
// ROWS=4 b64-gather amortization, persistent grid=256, RGRP=2, next group
// prefetched PACKED into 32 VGPRs during current group's gather+store,
// single 128 KB LDS tile flipped once per group.

#define IN_N   16384
#define OUT_N  16384
#define TPB    1024
#define ROWS   4
#define RGRP   2                   // row-groups per block: 2048/(ROWS*256)
#define GITERS (OUT_N / 4 / TPB)   // 4 neuron-quads per thread
#define SGRP   (IN_N / 4 / TPB)    // 4 float4 column-chunks per thread per row

typedef unsigned int u32;
typedef float f4 __attribute__((ext_vector_type(4)));

__global__ __launch_bounds__(256) void prep_kernel(const float* __restrict__ w,
                                                   const int* __restrict__ idx_a,
                                                   const int* __restrict__ idx_b,
                                                   uint2* __restrict__ pcoef,
                                                   uint4* __restrict__ pidx,
                                                   int nout) {
    int n = blockIdx.x * blockDim.x + threadIdx.x;
    if (n < nout) {
        const float4* wn4 = (const float4*)(w + (size_t)n * 16);
        float p[16];
        float4 w0 = wn4[0], w1 = wn4[1], w2 = wn4[2], w3 = wn4[3];
        p[0] = w0.x; p[1] = w0.y; p[2] = w0.z; p[3] = w0.w;
        p[4] = w1.x; p[5] = w1.y; p[6] = w1.z; p[7] = w1.w;
        p[8] = w2.x; p[9] = w2.y; p[10] = w2.z; p[11] = w2.w;
        p[12] = w3.x; p[13] = w3.y; p[14] = w3.z; p[15] = w3.w;
        float m = -1e30f;
#pragma unroll
        for (int i = 0; i < 16; ++i) m = fmaxf(m, p[i]);
        float s = 0.f;
#pragma unroll
        for (int i = 0; i < 16; ++i) { p[i] = __expf(p[i] - m); s += p[i]; }
        float inv = 1.f / s;
#pragma unroll
        for (int i = 0; i < 16; ++i) p[i] *= inv;
        // gates: 0, ab, a-ab, a, b-ab, b, a+b-2ab, a+b-ab,
        //        1-a-b+ab, 1-a-b+2ab, 1-b, 1-b+ab, 1-a, 1-a+ab, 1-ab, 1
        float c0 = p[8] + p[9] + p[10] + p[11] + p[12] + p[13] + p[14] + p[15];
        float c1 = p[2] + p[3] + p[6] + p[7] - p[8] - p[9] - p[12] - p[13];
        float c2 = p[4] + p[5] + p[6] + p[7] - p[8] - p[9] - p[10] - p[11];
        float c3 = p[1] - p[2] - p[4] - 2.f * p[6] - p[7]
                 + p[8] + 2.f * p[9] + p[11] + p[13] - p[14];
        uint2 r;
        r.x = __builtin_bit_cast(u32, __floats2half2_rn(c0, c1));
        r.y = __builtin_bit_cast(u32, __floats2half2_rn(c2, c3));
        pcoef[n] = r;
    }
    if (n < nout / 4) {
        int4 a = ((const int4*)idx_a)[n];
        int4 b = ((const int4*)idx_b)[n];
        uint4 r;
        r.x = (u32)a.x | ((u32)a.y << 16);
        r.y = (u32)a.z | ((u32)a.w << 16);
        r.z = (u32)b.x | ((u32)b.y << 16);
        r.w = (u32)b.z | ((u32)b.w << 16);
        pidx[n] = r;
    }
}

__device__ __forceinline__ float2 h2f(u32 bits) {
    return __half22float2(__builtin_bit_cast(__half2, bits));
}
__device__ __forceinline__ u32 pkh(float a, float b) {
    return __builtin_bit_cast(u32, __floats2half2_rn(a, b));
}

// one neuron, 4 rows: a/b are uint2 {rows01, rows23} fp16.
// returns {row0,row1,row2,row3} outputs. o = a*(c1+c3*b) + (c0+c2*b)
__device__ __forceinline__ f4 neuron4(uint2 a, uint2 b, float2 c01, float2 c23) {
    float2 aL = h2f(a.x), aH = h2f(a.y);
    float2 bL = h2f(b.x), bH = h2f(b.y);
    f4 o;
    o.x = fmaf(aL.x, fmaf(c23.y, bL.x, c01.y), fmaf(c23.x, bL.x, c01.x));
    o.y = fmaf(aL.y, fmaf(c23.y, bL.y, c01.y), fmaf(c23.x, bL.y, c01.x));
    o.z = fmaf(aH.x, fmaf(c23.y, bH.x, c01.y), fmaf(c23.x, bH.x, c01.x));
    o.w = fmaf(aH.y, fmaf(c23.y, bH.y, c01.y), fmaf(c23.x, bH.y, c01.x));
    return o;
}

// pack 4 rows' float4 (same column group) into 2 uint4 of column-interleaved fp16
__device__ __forceinline__ void pack4(const f4 v[ROWS], uint4& q0, uint4& q1) {
    q0.x = pkh(v[0].x, v[1].x); q0.y = pkh(v[2].x, v[3].x);
    q0.z = pkh(v[0].y, v[1].y); q0.w = pkh(v[2].y, v[3].y);
    q1.x = pkh(v[0].z, v[1].z); q1.y = pkh(v[2].z, v[3].z);
    q1.z = pkh(v[0].w, v[1].w); q1.w = pkh(v[2].w, v[3].w);
}

__global__ __launch_bounds__(TPB)
__attribute__((amdgpu_waves_per_eu(4, 4)))
void logic_kernel(const float* __restrict__ x,
                  const uint4* __restrict__ pidx,
                  const uint4* __restrict__ pcoef,
                  float* __restrict__ out) {
    __shared__ uint2 cols[IN_N];   // 128 KB: cols[i] = 4 rows of column i, fp16

    const int t = threadIdx.x;
    const int b0 = blockIdx.x * (ROWS * RGRP);

    // Gather indices: identical for every row-group, held in 16 VGPRs.
    uint4 id[GITERS];
#pragma unroll
    for (int k = 0; k < GITERS; ++k) id[k] = pidx[k * TPB + t];

    // Prologue: stage group 0 into LDS.
#pragma unroll
    for (int g = 0; g < SGRP; ++g) {
        int c4 = g * TPB + t;
        f4 v[ROWS];
#pragma unroll
        for (int j = 0; j < ROWS; ++j)
            v[j] = *((const f4*)(x + (size_t)(b0 + j) * IN_N) + c4);
        uint4 q0, q1;
        pack4(v, q0, q1);
        uint4* dst = (uint4*)&cols[c4 * 4];
        dst[0] = q0;
        dst[1] = q1;
    }
    __syncthreads();

    uint4 pk[SGRP][2];   // packed next-group tile: 32 VGPRs
    f4 ld[ROWS];         // in-flight chunk: 16 VGPRs

#pragma unroll
    for (int r = 0; r < RGRP; ++r) {
        const bool pf = (r + 1 < RGRP);
        float* ob = out + (size_t)(b0 + r * ROWS) * OUT_N;

#pragma unroll
        for (int k = 0; k < GITERS; ++k) {
            const int q = k * TPB + t;
            // (a) pack the chunk issued last iteration (frees ld before reuse)
            if (pf && k >= 1) pack4(ld, pk[k - 1][0], pk[k - 1][1]);
            // (b) issue this giter's chunk of NEXT group's rows
            if (pf) {
                const int c4 = k * TPB + t;
#pragma unroll
                for (int j = 0; j < ROWS; ++j)
                    ld[j] = *((const f4*)(x + (size_t)(b0 + (r + 1) * ROWS + j) * IN_N) + c4);
            }
            // (c) coefs from global (L2-resident 128 KB, latency hides under gathers)
            uint4 cA = pcoef[2 * q + 0];
            uint4 cB = pcoef[2 * q + 1];
            // (d) gather: one ds_read_b64 per index serves 4 rows
            uint2 A0 = cols[id[k].x & 0xffff], A1 = cols[id[k].x >> 16];
            uint2 A2 = cols[id[k].y & 0xffff], A3 = cols[id[k].y >> 16];
            uint2 B0 = cols[id[k].z & 0xffff], B1 = cols[id[k].z >> 16];
            uint2 B2 = cols[id[k].w & 0xffff], B3 = cols[id[k].w >> 16];
            f4 n0 = neuron4(A0, B0, h2f(cA.x), h2f(cA.y));
            f4 n1 = neuron4(A1, B1, h2f(cA.z), h2f(cA.w));
            f4 n2 = neuron4(A2, B2, h2f(cB.x), h2f(cB.y));
            f4 n3 = neuron4(A3, B3, h2f(cB.z), h2f(cB.w));
            f4 o0 = {n0.x, n1.x, n2.x, n3.x};
            f4 o1 = {n0.y, n1.y, n2.y, n3.y};
            f4 o2 = {n0.z, n1.z, n2.z, n3.z};
            f4 o3 = {n0.w, n1.w, n2.w, n3.w};
            *((f4*)(ob + 0 * (size_t)OUT_N) + q) = o0;
            *((f4*)(ob + 1 * (size_t)OUT_N) + q) = o1;
            *((f4*)(ob + 2 * (size_t)OUT_N) + q) = o2;
            *((f4*)(ob + 3 * (size_t)OUT_N) + q) = o3;
        }

        if (pf) {
            // pack the final in-flight chunk, flip the buffer
            pack4(ld, pk[SGRP - 1][0], pk[SGRP - 1][1]);
            __syncthreads();   // all gathers of group r done
#pragma unroll
            for (int g = 0; g < SGRP; ++g) {
                uint4* dst = (uint4*)&cols[(g * TPB + t) * 4];
                dst[0] = pk[g][0];
                dst[1] = pk[g][1];
            }
            __syncthreads();   // next group's tile visible
        }
    }
}

extern "C" void kernel_launch(void* const* d_in, const int* in_sizes, int n_in,
                              void* d_out, int out_size, void* d_ws, size_t ws_size,
                              hipStream_t stream) {
    const float* x = (const float*)d_in[0];       // (B, IN) fp32
    const float* w = (const float*)d_in[1];       // (OUT, 16) fp32
    const int* idx_a = (const int*)d_in[2];       // (OUT,) int32
    const int* idx_b = (const int*)d_in[3];       // (OUT,) int32

    const int nout = in_sizes[2];                 // 16384
    const int batch = in_sizes[0] / IN_N;         // 2048

    uint2* pcoef = (uint2*)d_ws;                              // 128 KB
    uint4* pidx  = (uint4*)((char*)d_ws + (size_t)nout * 8);  // 64 KB

    prep_kernel<<<(nout + 255) / 256, 256, 0, stream>>>(w, idx_a, idx_b,
                                                        pcoef, pidx, nout);
    logic_kernel<<<batch / (ROWS * RGRP), TPB, 0, stream>>>(x, pidx,
                                                            (const uint4*)pcoef,
                                                            (float*)d_out);
}

// Round 5
// 63.088 us; speedup vs baseline: 1.6813x; 1.6813x over previous
//
#include <hip/hip_runtime.h>
#include <hip/hip_fp16.h>

// LogicLayer: out[b,n] = C0[n] + C1[n]*a + C2[n]*b + C3[n]*a*b,
//   a = x[b, idx_a[n]], b = x[b, idx_b[n]], C = linear combos of softmax(w[n]).
//
// R9: R6-R8 post-mortem — at TPB=1024 the backend pins a 64-VGPR budget
// (launch_bounds(,4) and waves_per_eu(4,4) both ignored), so ANY persistent
// register prefetch state spills (WRITE_SIZE 219 vs 131 MB ideal). The LDS
// gather pipe itself is cheap (~3 us/CU, b32 or b64). The real R4 gap
// (61.8 vs 42.6 us duplex floor) is read-burst/write-burst phase
// serialization. Fix with ZERO persistent state: ROWS=2 -> two 64 KB LDS
// buffers; persistent grid=256, 8 rows/block, 4 windows of
// {stage(r+1)->other buf  ||  compute(r)->cur buf} + one barrier.
// Even waves run stage-then-compute, odd waves compute-then-stage, so read
// and write streams overlap throughout the window. Only id[] (16 VGPRs)
// persists; coefs re-read from L2-resident pcoef.

#define IN_N   16384
#define OUT_N  16384
#define TPB    1024
#define ROWS   2
#define GROUPS 4                   // rows per block = ROWS*GROUPS = 8
#define GITERS (OUT_N / 4 / TPB)   // 4 neuron-quads per thread per group
#define SGRP   (IN_N / 4 / TPB)    // 4 column-chunks (4 cols each) per thread

typedef unsigned int u32;
typedef float f4 __attribute__((ext_vector_type(4)));

__global__ __launch_bounds__(256) void prep_kernel(const float* __restrict__ w,
                                                   const int* __restrict__ idx_a,
                                                   const int* __restrict__ idx_b,
                                                   uint2* __restrict__ pcoef,
                                                   uint4* __restrict__ pidx,
                                                   int nout) {
    int n = blockIdx.x * blockDim.x + threadIdx.x;
    if (n < nout) {
        const float4* wn4 = (const float4*)(w + (size_t)n * 16);
        float p[16];
        float4 w0 = wn4[0], w1 = wn4[1], w2 = wn4[2], w3 = wn4[3];
        p[0] = w0.x; p[1] = w0.y; p[2] = w0.z; p[3] = w0.w;
        p[4] = w1.x; p[5] = w1.y; p[6] = w1.z; p[7] = w1.w;
        p[8] = w2.x; p[9] = w2.y; p[10] = w2.z; p[11] = w2.w;
        p[12] = w3.x; p[13] = w3.y; p[14] = w3.z; p[15] = w3.w;
        float m = -1e30f;
#pragma unroll
        for (int i = 0; i < 16; ++i) m = fmaxf(m, p[i]);
        float s = 0.f;
#pragma unroll
        for (int i = 0; i < 16; ++i) { p[i] = __expf(p[i] - m); s += p[i]; }
        float inv = 1.f / s;
#pragma unroll
        for (int i = 0; i < 16; ++i) p[i] *= inv;
        // gates: 0, ab, a-ab, a, b-ab, b, a+b-2ab, a+b-ab,
        //        1-a-b+ab, 1-a-b+2ab, 1-b, 1-b+ab, 1-a, 1-a+ab, 1-ab, 1
        float c0 = p[8] + p[9] + p[10] + p[11] + p[12] + p[13] + p[14] + p[15];
        float c1 = p[2] + p[3] + p[6] + p[7] - p[8] - p[9] - p[12] - p[13];
        float c2 = p[4] + p[5] + p[6] + p[7] - p[8] - p[9] - p[10] - p[11];
        float c3 = p[1] - p[2] - p[4] - 2.f * p[6] - p[7]
                 + p[8] + 2.f * p[9] + p[11] + p[13] - p[14];
        uint2 r;
        r.x = __builtin_bit_cast(u32, __floats2half2_rn(c0, c1));
        r.y = __builtin_bit_cast(u32, __floats2half2_rn(c2, c3));
        pcoef[n] = r;
    }
    if (n < nout / 4) {
        int4 a = ((const int4*)idx_a)[n];
        int4 b = ((const int4*)idx_b)[n];
        uint4 r;
        r.x = (u32)a.x | ((u32)a.y << 16);
        r.y = (u32)a.z | ((u32)a.w << 16);
        r.z = (u32)b.x | ((u32)b.y << 16);
        r.w = (u32)b.z | ((u32)b.w << 16);
        pidx[n] = r;
    }
}

__device__ __forceinline__ float2 h2f(u32 bits) {
    return __half22float2(__builtin_bit_cast(__half2, bits));
}
__device__ __forceinline__ u32 pkh(float a, float b) {
    return __builtin_bit_cast(u32, __floats2half2_rn(a, b));
}

// one neuron, 2 rows packed in one u32 (half2). o = a*(c1+c3*b) + (c0+c2*b)
__device__ __forceinline__ float2 neuron2(u32 a, u32 b, float2 c01, float2 c23) {
    float2 af = h2f(a), bf = h2f(b);
    float2 o;
    o.x = fmaf(af.x, fmaf(c23.y, bf.x, c01.y), fmaf(c23.x, bf.x, c01.x));
    o.y = fmaf(af.y, fmaf(c23.y, bf.y, c01.y), fmaf(c23.x, bf.y, c01.x));
    return o;
}

// Stage 2 rows of group r into buf: fp16 column-interleaved, transient regs only.
__device__ __forceinline__ void stage_group(const float* __restrict__ x,
                                            int b0, int r, u32* buf, int t) {
    const f4* x0 = (const f4*)(x + (size_t)(b0 + r * ROWS + 0) * IN_N);
    const f4* x1 = (const f4*)(x + (size_t)(b0 + r * ROWS + 1) * IN_N);
#pragma unroll
    for (int g = 0; g < SGRP; ++g) {
        int c4 = g * TPB + t;
        f4 v0 = x0[c4];
        f4 v1 = x1[c4];
        uint4 q;
        q.x = pkh(v0.x, v1.x);
        q.y = pkh(v0.y, v1.y);
        q.z = pkh(v0.z, v1.z);
        q.w = pkh(v0.w, v1.w);
        *(uint4*)&buf[c4 * 4] = q;
    }
}

// Gather + compute + store 2 rows of group r from buf.
__device__ __forceinline__ void compute_group(const u32* __restrict__ buf,
                                              const uint4* __restrict__ pcoef,
                                              const uint4* __restrict__ id,
                                              float* __restrict__ out,
                                              int b0, int r, int t) {
    f4* o0p = (f4*)(out + (size_t)(b0 + r * ROWS + 0) * OUT_N);
    f4* o1p = (f4*)(out + (size_t)(b0 + r * ROWS + 1) * OUT_N);
#pragma unroll
    for (int k = 0; k < GITERS; ++k) {
        int q = k * TPB + t;
        uint4 cA = pcoef[2 * q + 0];   // coefs for neurons 4q..4q+1
        uint4 cB = pcoef[2 * q + 1];   // coefs for neurons 4q+2..4q+3
        u32 A0 = buf[id[k].x & 0xffff], A1 = buf[id[k].x >> 16];
        u32 A2 = buf[id[k].y & 0xffff], A3 = buf[id[k].y >> 16];
        u32 B0 = buf[id[k].z & 0xffff], B1 = buf[id[k].z >> 16];
        u32 B2 = buf[id[k].w & 0xffff], B3 = buf[id[k].w >> 16];
        float2 r0 = neuron2(A0, B0, h2f(cA.x), h2f(cA.y));
        float2 r1 = neuron2(A1, B1, h2f(cA.z), h2f(cA.w));
        float2 r2 = neuron2(A2, B2, h2f(cB.x), h2f(cB.y));
        float2 r3 = neuron2(A3, B3, h2f(cB.z), h2f(cB.w));
        f4 o0, o1;
        o0.x = r0.x; o1.x = r0.y;
        o0.y = r1.x; o1.y = r1.y;
        o0.z = r2.x; o1.z = r2.y;
        o0.w = r3.x; o1.w = r3.y;
        o0p[q] = o0;
        o1p[q] = o1;
    }
}

__global__ __launch_bounds__(TPB) void logic_kernel(const float* __restrict__ x,
                                                    const uint4* __restrict__ pidx,
                                                    const uint4* __restrict__ pcoef,
                                                    float* __restrict__ out) {
    __shared__ u32 cols[2][IN_N];   // 2 x 64 KB: cols[b][i] = half2(row0,row1)

    const int t = threadIdx.x;
    const int b0 = blockIdx.x * (ROWS * GROUPS);
    const bool odd_wave = (t >> 6) & 1;

    // Gather indices: identical for every row-group; 16 VGPRs persistent.
    uint4 id[GITERS];
#pragma unroll
    for (int k = 0; k < GITERS; ++k) id[k] = pidx[k * TPB + t];

    // Head: stage group 0 into buffer 0.
    stage_group(x, b0, 0, cols[0], t);
    __syncthreads();

#pragma unroll
    for (int r = 0; r < GROUPS; ++r) {
        const bool pf = (r + 1 < GROUPS);
        u32* nbuf = cols[(r + 1) & 1];
        const u32* cbuf = cols[r & 1];
        // Alternate per-wave order so read (stage) and write (compute) streams
        // overlap inside the window instead of bursting sequentially.
        if (odd_wave) {
            compute_group(cbuf, pcoef, id, out, b0, r, t);
            if (pf) stage_group(x, b0, r + 1, nbuf, t);
        } else {
            if (pf) stage_group(x, b0, r + 1, nbuf, t);
            compute_group(cbuf, pcoef, id, out, b0, r, t);
        }
        __syncthreads();   // one barrier: nbuf visible AND cbuf free for reuse
    }
}

extern "C" void kernel_launch(void* const* d_in, const int* in_sizes, int n_in,
                              void* d_out, int out_size, void* d_ws, size_t ws_size,
                              hipStream_t stream) {
    const float* x = (const float*)d_in[0];       // (B, IN) fp32
    const float* w = (const float*)d_in[1];       // (OUT, 16) fp32
    const int* idx_a = (const int*)d_in[2];       // (OUT,) int32
    const int* idx_b = (const int*)d_in[3];       // (OUT,) int32

    const int nout = in_sizes[2];                 // 16384
    const int batch = in_sizes[0] / IN_N;         // 2048

    uint2* pcoef = (uint2*)d_ws;                              // 128 KB
    uint4* pidx  = (uint4*)((char*)d_ws + (size_t)nout * 8);  // 64 KB

    prep_kernel<<<(nout + 255) / 256, 256, 0, stream>>>(w, idx_a, idx_b,
                                                        pcoef, pidx, nout);
    logic_kernel<<<batch / (ROWS * GROUPS), TPB, 0, stream>>>(x, pidx,
                                                              (const uint4*)pcoef,
                                                              (float*)d_out);
}

// Round 7
// 56.758 us; speedup vs baseline: 1.8688x; 1.1115x over previous
//
#include <hip/hip_runtime.h>
#include <hip/hip_fp16.h>

// LogicLayer: out[b,n] = C0[n] + C1[n]*a + C2[n]*b + C3[n]*a*b,
//   a = x[b, idx_a[n]], b = x[b, idx_b[n]], C = linear combos of softmax(w[n]).
//
// R10 (resubmit — previous round died on container infra, no bench data):
// R9 post-mortem — spill fixed (WRITE=131MB clean) but time unchanged vs R4
// (63 vs 62): in-block scheduling doesn't matter. Counters show NO saturated
// pipe (HBM ~3.2 TB/s, VALU 9%, LDS ~4us): latency/structure bound. Common
// factor of R4/R9: ONE barrier-coupled 1024-thread block per CU — vmcnt(0)
// drains + head/tail leave memory idle with no co-resident block to fill
// gaps. Fix: many small INDEPENDENT blocks. TPB=512, ROWS=2, 64 KB LDS ->
// 2 blocks/CU co-resident, grid=1024, no persistent loop, no register state
// (pidx/pcoef are L2-resident, read in-loop). Block A's drain overlaps
// block B's issue; block turnover pipelines streams.
// A/B: if this still lands ~62, ~4.3 TB/s is the pattern's true ceiling.

#define IN_N   16384
#define OUT_N  16384
#define TPB    512
#define ROWS   2
#define GITERS (OUT_N / 4 / TPB)   // 8 neuron-quads per thread
#define SGRP   (IN_N / 4 / TPB)    // 8 column-chunks (4 cols each) per thread

typedef unsigned int u32;
typedef float f4 __attribute__((ext_vector_type(4)));

__global__ __launch_bounds__(256) void prep_kernel(const float* __restrict__ w,
                                                   const int* __restrict__ idx_a,
                                                   const int* __restrict__ idx_b,
                                                   uint2* __restrict__ pcoef,
                                                   uint4* __restrict__ pidx,
                                                   int nout) {
    int n = blockIdx.x * blockDim.x + threadIdx.x;
    if (n < nout) {
        const float4* wn4 = (const float4*)(w + (size_t)n * 16);
        float p[16];
        float4 w0 = wn4[0], w1 = wn4[1], w2 = wn4[2], w3 = wn4[3];
        p[0] = w0.x; p[1] = w0.y; p[2] = w0.z; p[3] = w0.w;
        p[4] = w1.x; p[5] = w1.y; p[6] = w1.z; p[7] = w1.w;
        p[8] = w2.x; p[9] = w2.y; p[10] = w2.z; p[11] = w2.w;
        p[12] = w3.x; p[13] = w3.y; p[14] = w3.z; p[15] = w3.w;
        float m = -1e30f;
#pragma unroll
        for (int i = 0; i < 16; ++i) m = fmaxf(m, p[i]);
        float s = 0.f;
#pragma unroll
        for (int i = 0; i < 16; ++i) { p[i] = __expf(p[i] - m); s += p[i]; }
        float inv = 1.f / s;
#pragma unroll
        for (int i = 0; i < 16; ++i) p[i] *= inv;
        // gates: 0, ab, a-ab, a, b-ab, b, a+b-2ab, a+b-ab,
        //        1-a-b+ab, 1-a-b+2ab, 1-b, 1-b+ab, 1-a, 1-a+ab, 1-ab, 1
        float c0 = p[8] + p[9] + p[10] + p[11] + p[12] + p[13] + p[14] + p[15];
        float c1 = p[2] + p[3] + p[6] + p[7] - p[8] - p[9] - p[12] - p[13];
        float c2 = p[4] + p[5] + p[6] + p[7] - p[8] - p[9] - p[10] - p[11];
        float c3 = p[1] - p[2] - p[4] - 2.f * p[6] - p[7]
                 + p[8] + 2.f * p[9] + p[11] + p[13] - p[14];
        uint2 r;
        r.x = __builtin_bit_cast(u32, __floats2half2_rn(c0, c1));
        r.y = __builtin_bit_cast(u32, __floats2half2_rn(c2, c3));
        pcoef[n] = r;
    }
    if (n < nout / 4) {
        int4 a = ((const int4*)idx_a)[n];
        int4 b = ((const int4*)idx_b)[n];
        uint4 r;
        r.x = (u32)a.x | ((u32)a.y << 16);
        r.y = (u32)a.z | ((u32)a.w << 16);
        r.z = (u32)b.x | ((u32)b.y << 16);
        r.w = (u32)b.z | ((u32)b.w << 16);
        pidx[n] = r;
    }
}

__device__ __forceinline__ float2 h2f(u32 bits) {
    return __half22float2(__builtin_bit_cast(__half2, bits));
}
__device__ __forceinline__ u32 pkh(float a, float b) {
    return __builtin_bit_cast(u32, __floats2half2_rn(a, b));
}

// one neuron, 2 rows packed in one u32 (half2). o = a*(c1+c3*b) + (c0+c2*b)
__device__ __forceinline__ float2 neuron2(u32 a, u32 b, float2 c01, float2 c23) {
    float2 af = h2f(a), bf = h2f(b);
    float2 o;
    o.x = fmaf(af.x, fmaf(c23.y, bf.x, c01.y), fmaf(c23.x, bf.x, c01.x));
    o.y = fmaf(af.y, fmaf(c23.y, bf.y, c01.y), fmaf(c23.x, bf.y, c01.x));
    return o;
}

__global__ __launch_bounds__(TPB) void logic_kernel(const float* __restrict__ x,
                                                    const uint4* __restrict__ pidx,
                                                    const uint4* __restrict__ pcoef,
                                                    float* __restrict__ out) {
    __shared__ u32 cols[IN_N];   // 64 KB: cols[i] = half2(row0,row1) of column i

    const int t = threadIdx.x;
    const int b0 = blockIdx.x * ROWS;

    // Stage 2 rows, fp16 column-interleaved.
    const f4* x0 = (const f4*)(x + (size_t)(b0 + 0) * IN_N);
    const f4* x1 = (const f4*)(x + (size_t)(b0 + 1) * IN_N);
#pragma unroll
    for (int g = 0; g < SGRP; ++g) {
        int c4 = g * TPB + t;
        f4 v0 = x0[c4];
        f4 v1 = x1[c4];
        uint4 q;
        q.x = pkh(v0.x, v1.x);
        q.y = pkh(v0.y, v1.y);
        q.z = pkh(v0.z, v1.z);
        q.w = pkh(v0.w, v1.w);
        *(uint4*)&cols[c4 * 4] = q;
    }
    __syncthreads();

    // Gather + compute + store. pidx/pcoef are L2-resident (64+128 KB shared
    // by all blocks); their latency hides under the gather/store stream.
    f4* o0p = (f4*)(out + (size_t)(b0 + 0) * OUT_N);
    f4* o1p = (f4*)(out + (size_t)(b0 + 1) * OUT_N);
#pragma unroll
    for (int k = 0; k < GITERS; ++k) {
        int q = k * TPB + t;
        uint4 idq = pidx[q];
        uint4 cA = pcoef[2 * q + 0];   // coefs for neurons 4q..4q+1
        uint4 cB = pcoef[2 * q + 1];   // coefs for neurons 4q+2..4q+3
        u32 A0 = cols[idq.x & 0xffff], A1 = cols[idq.x >> 16];
        u32 A2 = cols[idq.y & 0xffff], A3 = cols[idq.y >> 16];
        u32 B0 = cols[idq.z & 0xffff], B1 = cols[idq.z >> 16];
        u32 B2 = cols[idq.w & 0xffff], B3 = cols[idq.w >> 16];
        float2 r0 = neuron2(A0, B0, h2f(cA.x), h2f(cA.y));
        float2 r1 = neuron2(A1, B1, h2f(cA.z), h2f(cA.w));
        float2 r2 = neuron2(A2, B2, h2f(cB.x), h2f(cB.y));
        float2 r3 = neuron2(A3, B3, h2f(cB.z), h2f(cB.w));
        f4 o0, o1;
        o0.x = r0.x; o1.x = r0.y;
        o0.y = r1.x; o1.y = r1.y;
        o0.z = r2.x; o1.z = r2.y;
        o0.w = r3.x; o1.w = r3.y;
        o0p[q] = o0;
        o1p[q] = o1;
    }
}

extern "C" void kernel_launch(void* const* d_in, const int* in_sizes, int n_in,
                              void* d_out, int out_size, void* d_ws, size_t ws_size,
                              hipStream_t stream) {
    const float* x = (const float*)d_in[0];       // (B, IN) fp32
    const float* w = (const float*)d_in[1];       // (OUT, 16) fp32
    const int* idx_a = (const int*)d_in[2];       // (OUT,) int32
    const int* idx_b = (const int*)d_in[3];       // (OUT,) int32

    const int nout = in_sizes[2];                 // 16384
    const int batch = in_sizes[0] / IN_N;         // 2048

    uint2* pcoef = (uint2*)d_ws;                              // 128 KB
    uint4* pidx  = (uint4*)((char*)d_ws + (size_t)nout * 8);  // 64 KB

    prep_kernel<<<(nout + 255) / 256, 256, 0, stream>>>(w, idx_a, idx_b,
                                                        pcoef, pidx, nout);
    logic_kernel<<<batch / ROWS, TPB, 0, stream>>>(x, pidx, (const uint4*)pcoef,
                                                   (float*)d_out);
}